// Round 10
// baseline (381.437 us; speedup 1.0000x reference)
//
#include <hip/hip_runtime.h>

#define BB 256
#define SS 1024
#define TT 128
#define ST 126          // START state (column ST of trans = -1e4)
#define EN 127          // END state   (row EN of trans = -1e4)
#define IMIN -10000.0f
#define L2E 1.4426950408889634f
#define LN2f 0.6931471805599453f
#define QS 40           // padded quarter stride (floats); quarter bases hit
                        // disjoint bank groups (r3/r8: zero conflicts)

// One block per batch, 512 threads (8 waves, 2/SIMD). tid = 4*i + q:
// i = state row (0..127), q = j-quarter (32 P-coeffs per thread).
// v[j] = 2^(A[j]-sh) in LDS, sh block-uniform, anchored at state 0:
// dsh = log2(v[0]) -- uniform, NO reduce. Quad combine = DPP shuffles.
// r8/r9 lesson: source-ordered loads still got re-grouped (VGPR stuck at 40,
// 3-4 LDS latency exposures/step). Fix: sched_barrier(0) between the load
// block and all consumers -- loads must issue back-to-back (ONE exposure)
// and the allocator must keep 8 float4 destinations live.
__global__ __launch_bounds__(512, 1) void crf_fwd(const float* __restrict__ feats,
                                                  const int* __restrict__ blen,
                                                  const float* __restrict__ trans,
                                                  float* __restrict__ out)
{
    const int tid = threadIdx.x;
    const int i   = tid >> 2;    // state row
    const int q   = tid & 3;     // j-quarter
    const int b   = blockIdx.x;

    __shared__ __align__(16) float vbuf[2][4 * QS];
    __shared__ __align__(16) float featbuf[2][8 * TT];
    __shared__ __align__(16) float wout[TT];
    __shared__ __align__(16) float red[8];

    const float* fb = feats + (size_t)b * (SS * TT);
    const int L = blen[b];

    // stage feature chunk 0 (steps 0..7): 512 threads x float2 = 1024 floats
    *(float2*)(&featbuf[0][tid * 2]) = *(const float2*)(fb + tid * 2);
    float f0 = fb[i];   // step-0 feature (quad-broadcast dword)

    // quarter transition row -> registers, base-2 units
    float4 P0, P1, P2, P3, P4, P5, P6, P7;
    {
        const float* trow = trans + i * TT + q * 32;
        P0 = *(const float4*)(trow);      P1 = *(const float4*)(trow + 4);
        P2 = *(const float4*)(trow + 8);  P3 = *(const float4*)(trow + 12);
        P4 = *(const float4*)(trow + 16); P5 = *(const float4*)(trow + 20);
        P6 = *(const float4*)(trow + 24); P7 = *(const float4*)(trow + 28);
    }
#define SCALE4(Pv) Pv.x *= L2E; Pv.y *= L2E; Pv.z *= L2E; Pv.w *= L2E
    SCALE4(P0); SCALE4(P1); SCALE4(P2); SCALE4(P3);
    SCALE4(P4); SCALE4(P5); SCALE4(P6); SCALE4(P7);
#undef SCALE4

    // full-row max via quad reduce (DPP)
    float rm = -3.4e38f;
#define MAX4(Pv) rm = fmaxf(rm, fmaxf(fmaxf(Pv.x, Pv.y), fmaxf(Pv.z, Pv.w)))
    MAX4(P0); MAX4(P1); MAX4(P2); MAX4(P3);
    MAX4(P4); MAX4(P5); MAX4(P6); MAX4(P7);
#undef MAX4
    rm = fmaxf(rm, __shfl_xor(rm, 1));
    rm = fmaxf(rm, __shfl_xor(rm, 2));

    // normalize P, full-row sum S via quad reduce
    float S = 0.f;
#define NORM4(Pv) Pv.x = exp2f(Pv.x - rm); Pv.y = exp2f(Pv.y - rm); \
                  Pv.z = exp2f(Pv.z - rm); Pv.w = exp2f(Pv.w - rm); \
                  S += (Pv.x + Pv.y) + (Pv.z + Pv.w)
    NORM4(P0); NORM4(P1); NORM4(P2); NORM4(P3);
    NORM4(P4); NORM4(P5); NORM4(P6); NORM4(P7);
#undef NORM4
    S += __shfl_xor(S, 1);
    S += __shfl_xor(S, 2);

    // exact step 0 (alpha0 = delta on ST, col ST = -1e4 -> all scores ~ -1e4):
    // A1_i = f0*L2E + IMIN*L2E + log2(1 + sum_j 2^T2_ij), anchored at
    // rmc=max(rm,0) so row EN (rm=-14427) degrades gracefully (r4 NaN fix).
    float rmc = fmaxf(rm, 0.f);
    float A1 = fmaf(f0, L2E, (IMIN * L2E) + rmc +
                    log2f(fmaf(S, exp2f(rm - rmc), exp2f(-rmc))));

    if (tid == 0) red[0] = A1;    // anchor row for the uniform shift
    __syncthreads();              // also covers featbuf[0] staging
    float sh = red[0];
    if (q == 0) vbuf[0][(i >> 5) * QS + (i & 31)] = exp2f(A1 - sh); // v[0]=1 @ i=0
    __syncthreads();

    int cur = 0;
    float2 fnx = *(const float2*)(fb + 8 * TT + tid * 2);  // prefetch chunk 1

    for (int ch = 0; ; ++ch) {
        if (8 * ch + 8 < L) {
            // stage chunk ch+1 into the idle buffer; step barriers below
            // order it before its first read
            *(float2*)(&featbuf[(ch + 1) & 1][tid * 2]) = fnx;
            int cn = min(8 * ch + 16, SS - 8);
            fnx = *(const float2*)(fb + cn * TT + tid * 2);
        }
        const int sLo = (ch == 0) ? 1 : 8 * ch;
        const int sHi = min(8 * ch + 8, L);
        for (int s = sLo; s < sHi; ++s) {
            const float* vb = &vbuf[cur][q * QS];
            // ---- load block: 10 LDS reads, nothing else ----
            float v0f = vbuf[cur][0];
            float fv  = featbuf[ch & 1][((s & 7) << 7) + i];
            float4 v0 = *(const float4*)(vb);
            float4 v1 = *(const float4*)(vb + 4);
            float4 v2 = *(const float4*)(vb + 8);
            float4 v3 = *(const float4*)(vb + 12);
            float4 v4 = *(const float4*)(vb + 16);
            float4 v5 = *(const float4*)(vb + 20);
            float4 v6 = *(const float4*)(vb + 24);
            float4 v7 = *(const float4*)(vb + 28);
            // pin: all reads issue above, all consumers stay below ->
            // ONE LDS latency exposure, allocator keeps 8 float4 live
            __builtin_amdgcn_sched_barrier(0);

            float dsh = log2f(v0f);
            float cf  = exp2f(fmaf(fv, L2E, rm - dsh));

            float a0 = P0.x * v0.x, a1 = P0.y * v0.y;
            float a2 = P0.z * v0.z, a3 = P0.w * v0.w;
            a0 = fmaf(P1.x, v1.x, a0); a1 = fmaf(P1.y, v1.y, a1);
            a2 = fmaf(P1.z, v1.z, a2); a3 = fmaf(P1.w, v1.w, a3);
            a0 = fmaf(P2.x, v2.x, a0); a1 = fmaf(P2.y, v2.y, a1);
            a2 = fmaf(P2.z, v2.z, a2); a3 = fmaf(P2.w, v2.w, a3);
            a0 = fmaf(P3.x, v3.x, a0); a1 = fmaf(P3.y, v3.y, a1);
            a2 = fmaf(P3.z, v3.z, a2); a3 = fmaf(P3.w, v3.w, a3);
            a0 = fmaf(P4.x, v4.x, a0); a1 = fmaf(P4.y, v4.y, a1);
            a2 = fmaf(P4.z, v4.z, a2); a3 = fmaf(P4.w, v4.w, a3);
            a0 = fmaf(P5.x, v5.x, a0); a1 = fmaf(P5.y, v5.y, a1);
            a2 = fmaf(P5.z, v5.z, a2); a3 = fmaf(P5.w, v5.w, a3);
            a0 = fmaf(P6.x, v6.x, a0); a1 = fmaf(P6.y, v6.y, a1);
            a2 = fmaf(P6.z, v6.z, a2); a3 = fmaf(P6.w, v6.w, a3);
            a0 = fmaf(P7.x, v7.x, a0); a1 = fmaf(P7.y, v7.y, a1);
            a2 = fmaf(P7.z, v7.z, a2); a3 = fmaf(P7.w, v7.w, a3);

            float part = (a0 + a1) + (a2 + a3);
            part += __shfl_xor(part, 1);   // DPP quad-perm, no DS
            part += __shfl_xor(part, 2);

            float vn = cf * part;
            sh += dsh;
            if (q == 0) vbuf[cur ^ 1][(i >> 5) * QS + (i & 31)] = vn;
            __syncthreads();               // single barrier per step
            cur ^= 1;
        }
        if (8 * ch + 8 >= L) break;
    }

    // epilogue: out = ln2 * log2 sum_j 2^(sh + log2 v_j + trans[EN][j]*L2E)
    float vL = vbuf[cur][(i >> 5) * QS + (i & 31)];
    float w  = fmaf(trans[EN * TT + i], L2E, sh + log2f(vL)); // v=0 -> -inf ok
    if (q == 0) wout[i] = w;
    __syncthreads();
    if (tid < 64) {
        float w0 = wout[tid], w1 = wout[tid + 64];
        float mm = fmaxf(w0, w1);
        #pragma unroll
        for (int off = 1; off < 64; off <<= 1) mm = fmaxf(mm, __shfl_xor(mm, off));
        float ss = exp2f(w0 - mm) + exp2f(w1 - mm);
        #pragma unroll
        for (int off = 1; off < 64; off <<= 1) ss += __shfl_xor(ss, off);
        if (tid == 0) out[b] = (mm + log2f(ss)) * LN2f;
    }
}

extern "C" void kernel_launch(void* const* d_in, const int* in_sizes, int n_in,
                              void* d_out, int out_size, void* d_ws, size_t ws_size,
                              hipStream_t stream) {
    const float* feats = (const float*)d_in[0];
    const int*   blen  = (const int*)d_in[1];
    const float* trans = (const float*)d_in[2];
    float*       o     = (float*)d_out;
    crf_fwd<<<dim3(BB), dim3(512), 0, stream>>>(feats, blen, trans, o);
}